// Round 14
// baseline (266.315 us; speedup 1.0000x reference)
//
#include <hip/hip_runtime.h>
#include <hip/hip_bf16.h>

using u16 = unsigned short;
typedef __attribute__((ext_vector_type(8))) short short8;
typedef __attribute__((ext_vector_type(4))) float floatx4;
typedef __attribute__((ext_vector_type(4))) unsigned int uintx4;

__device__ __forceinline__ float b2f(u16 u) {
    union { unsigned int i; float f; } v; v.i = ((unsigned int)u) << 16; return v.f;
}
__device__ __forceinline__ u16 f2b(float f) {
    __hip_bfloat16 h = __float2bfloat16(f);
    u16 u; __builtin_memcpy(&u, &h, sizeof(u)); return u;
}

// B=4, fine 64x64x256, coarse 32x32x256, F=256, DG=8, KK=9, om ch=216
// Inputs fp32; OUTPUT fp32. fcu = concat(fine_cal, coarse_up) bf16 interleaved.
// wtf/wkt/wb0/bomw: weights in MFMA fragment order [ksg][ntile][lane][8].
// XCD-slab swizzle: XCD (bx&7) owns global rows [xcd*32, xcd*32+32).

// ---------------- k_pre: gap partials (128) | upsample (512) | wswz (896) -------
__global__ __launch_bounds__(256) void k_pre(const float* __restrict__ fine,
                                             const float* __restrict__ coarse,
                                             const float* __restrict__ fsw,
                                             const float* __restrict__ Wk,
                                             const float* __restrict__ omw,
                                             float* __restrict__ gap_part,
                                             u16* __restrict__ fcu,
                                             u16* __restrict__ wb0,
                                             u16* __restrict__ wkt,
                                             u16* __restrict__ bomw) {
    int bxg = blockIdx.x;
    int tid = threadIdx.x;
    if (bxg < 128) {
        int b = bxg >> 5, chunk = bxg & 31, c = tid;
        const float* p = fine + ((size_t)b * 4096 + (size_t)chunk * 128) * 256 + c;
        float s = 0.f;
        for (int i = 0; i < 128; i++) s += p[(size_t)i * 256];
        gap_part[(size_t)bxg * 256 + c] = s;
        return;
    }
    if (bxg < 640) {
        int p = (bxg - 128) * 32 + (tid >> 3);
        int ch = (tid & 7) * 32;
        int b = p >> 12, y = (p & 4095) >> 6, x = p & 63;
        float sy = fminf(fmaxf(0.5f * y - 0.25f, 0.0f), 31.0f);
        float sx = fminf(fmaxf(0.5f * x - 0.25f, 0.0f), 31.0f);
        int y0 = (int)floorf(sy); float wy = sy - (float)y0; int y1 = min(y0 + 1, 31);
        int x0 = (int)floorf(sx); float wx = sx - (float)x0; int x1 = min(x0 + 1, 31);
        float w00 = (1.f - wy) * (1.f - wx), w01 = (1.f - wy) * wx;
        float w10 = wy * (1.f - wx), w11 = wy * wx;
        const float* c00 = coarse + ((size_t)((b * 32 + y0) * 32 + x0)) * 256 + ch;
        const float* c01 = coarse + ((size_t)((b * 32 + y0) * 32 + x1)) * 256 + ch;
        const float* c10 = coarse + ((size_t)((b * 32 + y1) * 32 + x0)) * 256 + ch;
        const float* c11 = coarse + ((size_t)((b * 32 + y1) * 32 + x1)) * 256 + ch;
        u16* dst = fcu + (size_t)p * 512 + 256 + ch;
        #pragma unroll
        for (int k = 0; k < 4; k++) {
            float4 a0 = *(const float4*)(c00 + k * 8), a1v = *(const float4*)(c00 + k * 8 + 4);
            float4 b0 = *(const float4*)(c01 + k * 8), b1v = *(const float4*)(c01 + k * 8 + 4);
            float4 g0 = *(const float4*)(c10 + k * 8), g1 = *(const float4*)(c10 + k * 8 + 4);
            float4 d0 = *(const float4*)(c11 + k * 8), d1 = *(const float4*)(c11 + k * 8 + 4);
            u16 o[8] = {
                f2b(w00 * a0.x + w01 * b0.x + w10 * g0.x + w11 * d0.x),
                f2b(w00 * a0.y + w01 * b0.y + w10 * g0.y + w11 * d0.y),
                f2b(w00 * a0.z + w01 * b0.z + w10 * g0.z + w11 * d0.z),
                f2b(w00 * a0.w + w01 * b0.w + w10 * g0.w + w11 * d0.w),
                f2b(w00 * a1v.x + w01 * b1v.x + w10 * g1.x + w11 * d1.x),
                f2b(w00 * a1v.y + w01 * b1v.y + w10 * g1.y + w11 * d1.y),
                f2b(w00 * a1v.z + w01 * b1v.z + w10 * g1.z + w11 * d1.z),
                f2b(w00 * a1v.w + w01 * b1v.w + w10 * g1.w + w11 * d1.w)};
            uint4 ov; __builtin_memcpy(&ov, o, 16);
            *(uint4*)(dst + k * 8) = ov;
        }
        return;
    }
    int bx = bxg - 640;
    if (bx < 32) {
        int idx = bx * 256 + tid;
        int lane = idx & 63, nt = (idx >> 6) & 15, ks = idx >> 10;
        int n = nt * 16 + (lane & 15);
        int k0 = ks * 32 + (lane >> 4) * 8;
        u16 tmp[8];
        #pragma unroll
        for (int j = 0; j < 8; j++) tmp[j] = f2b(fsw[(size_t)(k0 + j) * 256 + n]);
        uint4 v; __builtin_memcpy(&v, tmp, 16);
        *(uint4*)(wb0 + (size_t)idx * 8) = v;
    } else if (bx < 320) {
        int idx = (bx - 32) * 256 + tid;
        int lane = idx & 63, nt = (idx >> 6) & 15, ks = idx >> 10;
        int n = nt * 16 + (lane & 15);
        int k0 = ks * 32 + (lane >> 4) * 8;
        u16 tmp[8];
        #pragma unroll
        for (int j = 0; j < 8; j++) tmp[j] = f2b(Wk[(size_t)(k0 + j) * 256 + n]);
        uint4 v; __builtin_memcpy(&v, tmp, 16);
        *(uint4*)(wkt + (size_t)idx * 8) = v;
    } else {
        int idx = (bx - 320) * 256 + tid;
        int lane = idx & 63, nt = (idx >> 6) & 15, ks = (idx >> 10) & 15, t = idx >> 14;
        int n = nt * 16 + (lane & 15);
        int f0 = ks * 32 + (lane >> 4) * 8;
        u16 tmp[8];
        #pragma unroll
        for (int j = 0; j < 8; j++)
            tmp[j] = (n < 216) ? f2b(omw[((size_t)t * 512 + f0 + j) * 216 + n]) : (u16)0;
        uint4 v; __builtin_memcpy(&v, tmp, 16);
        *(uint4*)(bomw + (size_t)idx * 8) = v;
    }
}

// ---------------- k_mid: g0 (512, with inline attn GEMV) | weff (144) -----------
__global__ __launch_bounds__(256) void k_mid(const float* __restrict__ fine,
                                             const float* __restrict__ gap_part,
                                             const float* __restrict__ attw,
                                             const u16* __restrict__ wb,
                                             u16* __restrict__ fcu,
                                             const float* __restrict__ ow,
                                             const u16* __restrict__ bomw,
                                             u16* __restrict__ wtf) {
    __shared__ u16 smem[32 * 520];
    int bxg = blockIdx.x;
    int tid = threadIdx.x;
    int lane = tid & 63, wid = tid >> 6;
    int r = lane & 15, quad = lane >> 4;
    if (bxg < 512) {
        u16* cols = smem;
        float* gaprow = (float*)(smem + 32 * 264);
        float* a1row  = (float*)(smem + 32 * 264 + 512);
        int m0 = bxg * 32;
        int b = m0 >> 12;
        {
            const float* gp = gap_part + (size_t)b * 32 * 256 + tid;
            float gsum = 0.f;
            #pragma unroll
            for (int k = 0; k < 32; k++) gsum += gp[(size_t)k * 256];
            gaprow[tid] = gsum;
        }
        __syncthreads();
        {
            const float* wcol = attw + tid;
            float s = 0.f;
            #pragma unroll 8
            for (int c = 0; c < 256; c++) s += gaprow[c] * wcol[(size_t)c * 256];
            s *= (1.0f / 4096.0f);
            a1row[tid] = 1.0f + 1.0f / (1.0f + expf(-s));
        }
        __syncthreads();
        int sp = tid >> 3, coff = (tid & 7) * 32;
        int row = m0 + sp;
        {
            const float* src = fine + (size_t)row * 256 + coff;
            u16* dst = &cols[sp * 264 + coff];
            #pragma unroll
            for (int ch = 0; ch < 4; ch++) {
                float4 v0 = *(const float4*)(src + ch * 8);
                float4 v1 = *(const float4*)(src + ch * 8 + 4);
                float4 s0 = *(const float4*)(&a1row[coff + ch * 8]);
                float4 s1 = *(const float4*)(&a1row[coff + ch * 8 + 4]);
                u16 o[8] = {f2b(v0.x * s0.x), f2b(v0.y * s0.y), f2b(v0.z * s0.z), f2b(v0.w * s0.w),
                            f2b(v1.x * s1.x), f2b(v1.y * s1.y), f2b(v1.z * s1.z), f2b(v1.w * s1.w)};
                uint4 ov; __builtin_memcpy(&ov, o, 16);
                *(uint4*)(dst + ch * 8) = ov;
            }
        }
        __syncthreads();
        floatx4 acc[2][4];
        #pragma unroll
        for (int i = 0; i < 2; i++)
            #pragma unroll
            for (int j = 0; j < 4; j++) acc[i][j] = (floatx4){0.f, 0.f, 0.f, 0.f};
        #pragma unroll
        for (int ks = 0; ks < 8; ks++) {
            short8 a0 = *(const short8*)&cols[r * 264 + ks * 32 + quad * 8];
            short8 a1v = *(const short8*)&cols[(16 + r) * 264 + ks * 32 + quad * 8];
            const u16* bp = wb + (((size_t)ks * 16 + wid * 4) * 64 + lane) * 8;
            short8 b0 = *(const short8*)(bp);
            short8 b1 = *(const short8*)(bp + 512);
            short8 b2 = *(const short8*)(bp + 1024);
            short8 b3 = *(const short8*)(bp + 1536);
            acc[0][0] = __builtin_amdgcn_mfma_f32_16x16x32_bf16(a0, b0, acc[0][0], 0, 0, 0);
            acc[0][1] = __builtin_amdgcn_mfma_f32_16x16x32_bf16(a0, b1, acc[0][1], 0, 0, 0);
            acc[0][2] = __builtin_amdgcn_mfma_f32_16x16x32_bf16(a0, b2, acc[0][2], 0, 0, 0);
            acc[0][3] = __builtin_amdgcn_mfma_f32_16x16x32_bf16(a0, b3, acc[0][3], 0, 0, 0);
            acc[1][0] = __builtin_amdgcn_mfma_f32_16x16x32_bf16(a1v, b0, acc[1][0], 0, 0, 0);
            acc[1][1] = __builtin_amdgcn_mfma_f32_16x16x32_bf16(a1v, b1, acc[1][1], 0, 0, 0);
            acc[1][2] = __builtin_amdgcn_mfma_f32_16x16x32_bf16(a1v, b2, acc[1][2], 0, 0, 0);
            acc[1][3] = __builtin_amdgcn_mfma_f32_16x16x32_bf16(a1v, b3, acc[1][3], 0, 0, 0);
        }
        #pragma unroll
        for (int mt = 0; mt < 2; mt++)
            #pragma unroll
            for (int nt = 0; nt < 4; nt++) {
                int f = wid * 64 + nt * 16 + r;
                #pragma unroll
                for (int reg = 0; reg < 4; reg++) {
                    int pp = m0 + mt * 16 + quad * 4 + reg;
                    fcu[(size_t)pp * 512 + f] = f2b(acc[mt][nt][reg]);
                }
            }
        return;
    }
    int i = bxg - 512;
    int c0 = (i & 15) * 32, t = i >> 4;
    u16* cols = smem;
    int sp = tid >> 3, f0 = (tid & 7) * 64;
    {
        const float* src = ow + (size_t)(c0 + sp) * 512 + f0;
        u16* dst = &cols[sp * 520 + f0];
        #pragma unroll
        for (int k = 0; k < 8; k++) {
            float4 v0 = *(const float4*)(src + k * 8);
            float4 v1 = *(const float4*)(src + k * 8 + 4);
            u16 o[8] = {f2b(v0.x), f2b(v0.y), f2b(v0.z), f2b(v0.w),
                        f2b(v1.x), f2b(v1.y), f2b(v1.z), f2b(v1.w)};
            uint4 ov; __builtin_memcpy(&ov, o, 16);
            *(uint4*)(dst + k * 8) = ov;
        }
    }
    __syncthreads();
    floatx4 acc[2][4];
    #pragma unroll
    for (int ii = 0; ii < 2; ii++)
        #pragma unroll
        for (int j = 0; j < 4; j++) acc[ii][j] = (floatx4){0.f, 0.f, 0.f, 0.f};
    #pragma unroll
    for (int ks = 0; ks < 16; ks++) {
        short8 a0 = *(const short8*)&cols[r * 520 + ks * 32 + quad * 8];
        short8 a1v = *(const short8*)&cols[(16 + r) * 520 + ks * 32 + quad * 8];
        const u16* bp = bomw + (((size_t)(t * 16 + ks) * 16 + wid * 4) * 64 + lane) * 8;
        short8 b0 = *(const short8*)(bp);
        short8 b1 = *(const short8*)(bp + 512);
        short8 b2 = *(const short8*)(bp + 1024);
        short8 b3 = *(const short8*)(bp + 1536);
        acc[0][0] = __builtin_amdgcn_mfma_f32_16x16x32_bf16(a0, b0, acc[0][0], 0, 0, 0);
        acc[0][1] = __builtin_amdgcn_mfma_f32_16x16x32_bf16(a0, b1, acc[0][1], 0, 0, 0);
        acc[0][2] = __builtin_amdgcn_mfma_f32_16x16x32_bf16(a0, b2, acc[0][2], 0, 0, 0);
        acc[0][3] = __builtin_amdgcn_mfma_f32_16x16x32_bf16(a0, b3, acc[0][3], 0, 0, 0);
        acc[1][0] = __builtin_amdgcn_mfma_f32_16x16x32_bf16(a1v, b0, acc[1][0], 0, 0, 0);
        acc[1][1] = __builtin_amdgcn_mfma_f32_16x16x32_bf16(a1v, b1, acc[1][1], 0, 0, 0);
        acc[1][2] = __builtin_amdgcn_mfma_f32_16x16x32_bf16(a1v, b2, acc[1][2], 0, 0, 0);
        acc[1][3] = __builtin_amdgcn_mfma_f32_16x16x32_bf16(a1v, b3, acc[1][3], 0, 0, 0);
    }
    #pragma unroll
    for (int mt = 0; mt < 2; mt++) {
        #pragma unroll
        for (int nt = 0; nt < 4; nt++) {
            int n = wid * 64 + nt * 16 + r;
            #pragma unroll
            for (int reg = 0; reg < 4; reg++) {
                int c = c0 + mt * 16 + quad * 4 + reg;
                float sc = (c >= 256) ? 2.0f : 1.0f;
                size_t addr = (((size_t)(t * 16 + (c >> 5)) * 16 + (n >> 4)) * 64
                               + ((c >> 3) & 3) * 16 + (n & 15)) * 8 + (c & 7);
                wtf[addr] = f2b(acc[mt][nt][reg] * sc);
            }
        }
    }
}

// ---------------- stage 5: halo conv, M=32, DUAL-K-STREAM, grid 1024 ------------
// Rounds 8-11: occupancy and prefetch schemes all flat; invariant = serial MFMA
// accumulator chains + A-read feeding the very next MFMA. Fix the ILP at the
// ACCUMULATOR level (RA cannot fold it): process K-quads cq and cq+8 per
// iteration with SEPARATE acc sets (summed fp32 at the end). 8 independent
// MFMA chains; half-1's A-reads overlap half-0's MFMAs. Outer iterations 16->8
// (halves barrier-drain). Pixel stride padded to 72 u16 (144B) to avoid the
// 128B bank-wrap (all pixels would alias to the same 4 banks).
__global__ __launch_bounds__(256, 4) void k_conv(const u16* __restrict__ fcu,
                                                 const u16* __restrict__ wtf,
                                                 const float* __restrict__ bias,
                                                 float* __restrict__ om) {
    __shared__ u16 halo[2][60 * 72];
    int tid = threadIdx.x;
    int bx = blockIdx.x;
    int xcd = bx & 7, i = bx >> 3;            // i in 0..127
    int prow4 = xcd * 8 + (i >> 4);           // 4-row group 0..63
    int pcol = (i >> 1) & 7;
    int ns = i & 1;
    int b = prow4 >> 4;
    int py0 = (prow4 & 15) * 4, px0 = pcol * 8;
    int n0 = ns * 128;
    int lane = tid & 63, wid = tid >> 6;
    int r = lane & 15, quad = lane >> 4;

    int pix0 = tid >> 2, q80 = tid & 3;
    int hy0 = pix0 / 10, hx0 = pix0 - hy0 * 10;
    int gy0 = py0 - 1 + hy0, gx0 = px0 - 1 + hx0;
    bool act0 = pix0 < 60;
    bool in0 = act0 && gy0 >= 0 && gy0 < 64 && gx0 >= 0 && gx0 < 64;
    const u16* gs0 = fcu + ((size_t)((b * 64 + min(max(gy0, 0), 63)) * 64 + min(max(gx0, 0), 63))) * 512 + q80 * 8;
    int ld0 = pix0 * 72 + q80 * 8;            // h=0 slot; h=1 at +32

    floatx4 acc2[2][2][2];                    // [h][mt][nt] - independent chains
    #pragma unroll
    for (int h = 0; h < 2; h++)
        #pragma unroll
        for (int a = 0; a < 2; a++)
            #pragma unroll
            for (int c = 0; c < 2; c++) acc2[h][a][c] = (floatx4){0.f, 0.f, 0.f, 0.f};

    {
        uint4 v0 = make_uint4(0, 0, 0, 0), v1 = make_uint4(0, 0, 0, 0);
        if (in0) { v0 = *(const uint4*)(gs0); v1 = *(const uint4*)(gs0 + 256); }
        if (act0) { *(uint4*)&halo[0][ld0] = v0; *(uint4*)&halo[0][ld0 + 32] = v1; }
    }
    __syncthreads();

    for (int cq = 0; cq < 8; cq++) {
        int cur = cq & 1;
        const u16* hb = &halo[cur][0];
        // B prefetch, depth-2 taps x 2 halves
        short8 Bp[2][2][2];                   // [d][h][ntile]
        #pragma unroll
        for (int d = 0; d < 2; d++)
            #pragma unroll
            for (int h = 0; h < 2; h++) {
                const u16* bp = wtf + (((size_t)(d * 16 + cq + h * 8) * 16 + ns * 8 + wid * 2) * 64 + lane) * 8;
                Bp[d][h][0] = *(const short8*)(bp);
                Bp[d][h][1] = *(const short8*)(bp + 512);
            }
        uint4 v0 = make_uint4(0, 0, 0, 0), v1 = make_uint4(0, 0, 0, 0);
        #pragma unroll
        for (int t = 0; t < 9; t++) {
            int d = t & 1;
            short8 b00 = Bp[d][0][0], b01 = Bp[d][0][1];
            short8 b10 = Bp[d][1][0], b11 = Bp[d][1][1];
            int dy = t / 3 - 1, dx = t - (t / 3) * 3 - 1;
            short8 a[2][2];                   // [h][mt]
            #pragma unroll
            for (int mt = 0; mt < 2; mt++) {
                int m = mt * 16 + r;
                int hy = (m >> 3) + 1 + dy, hx = (m & 7) + 1 + dx;
                int base = (hy * 10 + hx) * 72 + quad * 8;
                a[0][mt] = *(const short8*)&hb[base];
                a[1][mt] = *(const short8*)&hb[base + 32];
            }
            // B prefetch for t+2
            if (t < 7) {
                #pragma unroll
                for (int h = 0; h < 2; h++) {
                    const u16* bp = wtf + (((size_t)((t + 2) * 16 + cq + h * 8) * 16 + ns * 8 + wid * 2) * 64 + lane) * 8;
                    Bp[d][h][0] = *(const short8*)(bp);
                    Bp[d][h][1] = *(const short8*)(bp + 512);
                }
            }
            if (t == 5 && cq < 7) {
                if (in0) {
                    v0 = *(const uint4*)(gs0 + (cq + 1) * 32);
                    v1 = *(const uint4*)(gs0 + (cq + 9) * 32);
                }
            }
            acc2[0][0][0] = __builtin_amdgcn_mfma_f32_16x16x32_bf16(a[0][0], b00, acc2[0][0][0], 0, 0, 0);
            acc2[1][0][0] = __builtin_amdgcn_mfma_f32_16x16x32_bf16(a[1][0], b10, acc2[1][0][0], 0, 0, 0);
            acc2[0][0][1] = __builtin_amdgcn_mfma_f32_16x16x32_bf16(a[0][0], b01, acc2[0][0][1], 0, 0, 0);
            acc2[1][0][1] = __builtin_amdgcn_mfma_f32_16x16x32_bf16(a[1][0], b11, acc2[1][0][1], 0, 0, 0);
            acc2[0][1][0] = __builtin_amdgcn_mfma_f32_16x16x32_bf16(a[0][1], b00, acc2[0][1][0], 0, 0, 0);
            acc2[1][1][0] = __builtin_amdgcn_mfma_f32_16x16x32_bf16(a[1][1], b10, acc2[1][1][0], 0, 0, 0);
            acc2[0][1][1] = __builtin_amdgcn_mfma_f32_16x16x32_bf16(a[0][1], b01, acc2[0][1][1], 0, 0, 0);
            acc2[1][1][1] = __builtin_amdgcn_mfma_f32_16x16x32_bf16(a[1][1], b11, acc2[1][1][1], 0, 0, 0);
        }
        if (cq < 7) {
            if (act0) { *(uint4*)&halo[cur ^ 1][ld0] = v0; *(uint4*)&halo[cur ^ 1][ld0 + 32] = v1; }
        }
        __syncthreads();
    }
    #pragma unroll
    for (int nt = 0; nt < 2; nt++) {
        int n = n0 + wid * 32 + nt * 16 + r;
        if (n < 216) {
            float bv = bias[n];
            #pragma unroll
            for (int mt = 0; mt < 2; mt++) {
                #pragma unroll
                for (int reg = 0; reg < 4; reg++) {
                    int m = mt * 16 + quad * 4 + reg;
                    int gyy = py0 + (m >> 3), gxx = px0 + (m & 7);
                    size_t pix = (size_t)((b * 64 + gyy) * 64 + gxx);
                    om[pix * 216 + n] = acc2[0][mt][nt][reg] + acc2[1][mt][nt][reg] + bv;
                }
            }
        }
    }
}

// ---------------- stage 6 helpers -----------------------------------------------
#define KEEP8(G) asm volatile("" :: "v"((G)[0][0]), "v"((G)[0][1]), \
                                    "v"((G)[1][0]), "v"((G)[1][1]), \
                                    "v"((G)[2][0]), "v"((G)[2][1]), \
                                    "v"((G)[3][0]), "v"((G)[3][1]))

__device__ __forceinline__ void dcn_addr1(int g3, int tl, int y, int xs, int ch0,
                                          float oy, float ox, float mlog,
                                          float w[4], int ofs[4]) {
    int dy = g3 - 1, dx = tl - 1;
    float mk = 2.0f / (1.0f + expf(-mlog));
    float py = (float)(y + dy) + oy;
    float px = (float)(xs + dx) + ox;
    float fy = floorf(py), fx = floorf(px);
    int iy = (int)fy, ix = (int)fx;
    float wy1 = py - fy, wx1 = px - fx;
    float wy0 = 1.f - wy1, wx0 = 1.f - wx1;
    bool y0in = iy >= 0 && iy < 64, y1in = iy >= -1 && iy < 63;
    bool x0in = ix >= 0 && ix < 64, x1in = ix >= -1 && ix < 63;
    w[0] = (y0in && x0in) ? wy0 * wx0 * mk : 0.f;
    w[1] = (y0in && x1in) ? wy0 * wx1 * mk : 0.f;
    w[2] = (y1in && x0in) ? wy1 * wx0 * mk : 0.f;
    w[3] = (y1in && x1in) ? wy1 * wx1 * mk : 0.f;
    int iy0 = min(max(iy, 0), 63), iy1 = min(max(iy + 1, 0), 63);
    int ix0 = min(max(ix, 0), 63), ix1 = min(max(ix + 1, 0), 63);
    ofs[0] = (iy0 * 64 + ix0) * 512 + ch0;
    ofs[1] = (iy0 * 64 + ix1) * 512 + ch0;
    ofs[2] = (iy1 * 64 + ix0) * 512 + ch0;
    ofs[3] = (iy1 * 64 + ix1) * 512 + ch0;
}

__device__ __forceinline__ void dcn_issue(uintx4 G[4][2], const u16* __restrict__ cub,
                                          const int ofs[4]) {
    #pragma unroll
    for (int c = 0; c < 4; c++) {
        const u16* p = cub + ofs[c];
        G[c][0] = *(const uintx4*)(p);
        G[c][1] = *(const uintx4*)(p + 8);
    }
}

__device__ __forceinline__ void dcn_blend(const uintx4 G[4][2], const float w[4],
                                          u16* __restrict__ dst) {
    #pragma unroll
    for (int k = 0; k < 2; k++) {
        const u16* q0 = (const u16*)&G[0][k];
        const u16* q1 = (const u16*)&G[1][k];
        const u16* q2 = (const u16*)&G[2][k];
        const u16* q3 = (const u16*)&G[3][k];
        u16 o[8];
        #pragma unroll
        for (int j = 0; j < 8; j++) {
            float v = w[0] * b2f(q0[j]) + w[1] * b2f(q1[j])
                    + w[2] * b2f(q2[j]) + w[3] * b2f(q3[j]);
            o[j] = f2b(v);
        }
        uint4 ov; __builtin_memcpy(&ov, o, 16);
        *(uint4*)(dst + k * 8) = ov;
    }
}

// ---------------- stage 6: fused DCN, keepalive-forced depth-2 gather pipeline --
__global__ __launch_bounds__(512, 2) void k_dcn(const u16* __restrict__ fcu,
                                                const float* __restrict__ om,
                                                const u16* __restrict__ bfr,
                                                const float* __restrict__ bias,
                                                float* __restrict__ out) {
    __shared__ u16 cols[32 * 776];
    int tid = threadIdx.x;
    int bx = blockIdx.x;
    int xcd = bx & 7, i = bx >> 3;             // i in 0..63
    int grow = xcd * 32 + (i >> 1);            // global row 0..255
    int p0 = grow * 64 + (i & 1) * 32;         // 32-pixel strip
    int b = p0 >> 12;
    int y = (p0 & 4095) >> 6;
    int x0 = p0 & 63;
    int lane = tid & 63, wid = tid >> 6;       // wid 0..7
    int r = lane & 15, quad = lane >> 4;
    int sp = tid >> 4;                          // pixel in strip 0..31
    int sgh = tid & 15;                         // group-half
    int g = sgh >> 1, h = sgh & 1;
    int ch0 = g * 32 + h * 16;
    int pix = p0 + sp;
    int xs = x0 + sp;
    const u16* cub = fcu + ((size_t)b * 4096) * 512 + 256;
    const float* omp = om + (size_t)pix * 216;
    u16* mydst = &cols[0] + sp * 776 + ch0;

    floatx4 acc[2][2];
    #pragma unroll
    for (int a = 0; a < 2; a++)
        #pragma unroll
        for (int c = 0; c < 2; c++) acc[a][c] = (floatx4){0.f, 0.f, 0.f, 0.f};

    #pragma unroll
    for (int g3 = 0; g3 < 3; g3++) {
        float oy[3], ox[3], mm[3];
        #pragma unroll
        for (int tl = 0; tl < 3; tl++) {
            int t = g3 * 3 + tl;
            oy[tl] = omp[g * 18 + 2 * t];
            ox[tl] = omp[g * 18 + 2 * t + 1];
            mm[tl] = omp[144 + g * 9 + t];
        }
        float w0[4], w1[4], w2[4];
        int o0[4], o1[4], o2[4];
        uintx4 G0[4][2], G1[4][2], G2[4][2];
        dcn_addr1(g3, 0, y, xs, ch0, oy[0], ox[0], mm[0], w0, o0);
        dcn_issue(G0, cub, o0);
        dcn_addr1(g3, 1, y, xs, ch0, oy[1], ox[1], mm[1], w1, o1);
        dcn_issue(G1, cub, o1);
        __builtin_amdgcn_sched_barrier(0);
        KEEP8(G0);
        __builtin_amdgcn_sched_barrier(0);
        dcn_blend(G0, w0, mydst + 0 * 256);
        dcn_addr1(g3, 2, y, xs, ch0, oy[2], ox[2], mm[2], w2, o2);
        dcn_issue(G2, cub, o2);
        __builtin_amdgcn_sched_barrier(0);
        KEEP8(G1);
        __builtin_amdgcn_sched_barrier(0);
        dcn_blend(G1, w1, mydst + 1 * 256);
        KEEP8(G2);
        __builtin_amdgcn_sched_barrier(0);
        dcn_blend(G2, w2, mydst + 2 * 256);
        __syncthreads();
        short8 Bb[4][2];
        #pragma unroll
        for (int d = 0; d < 4; d++) {
            const u16* bp = bfr + (((size_t)(g3 * 24 + d) * 16 + wid * 2) * 64 + lane) * 8;
            Bb[d][0] = *(const short8*)(bp);
            Bb[d][1] = *(const short8*)(bp + 512);
        }
        #pragma unroll
        for (int ksl = 0; ksl < 24; ksl++) {
            int d = ksl & 3;
            short8 b0 = Bb[d][0], b1 = Bb[d][1];
            if (ksl + 4 < 24) {
                const u16* bp = bfr + (((size_t)(g3 * 24 + ksl + 4) * 16 + wid * 2) * 64 + lane) * 8;
                Bb[d][0] = *(const short8*)(bp);
                Bb[d][1] = *(const short8*)(bp + 512);
            }
            short8 a0 = *(const short8*)&cols[r * 776 + ksl * 32 + quad * 8];
            short8 a1 = *(const short8*)&cols[(16 + r) * 776 + ksl * 32 + quad * 8];
            acc[0][0] = __builtin_amdgcn_mfma_f32_16x16x32_bf16(a0, b0, acc[0][0], 0, 0, 0);
            acc[0][1] = __builtin_amdgcn_mfma_f32_16x16x32_bf16(a0, b1, acc[0][1], 0, 0, 0);
            acc[1][0] = __builtin_amdgcn_mfma_f32_16x16x32_bf16(a1, b0, acc[1][0], 0, 0, 0);
            acc[1][1] = __builtin_amdgcn_mfma_f32_16x16x32_bf16(a1, b1, acc[1][1], 0, 0, 0);
        }
        __syncthreads();
    }
    #pragma unroll
    for (int mt = 0; mt < 2; mt++) {
        #pragma unroll
        for (int nt = 0; nt < 2; nt++) {
            int f = wid * 32 + nt * 16 + r;
            float bv = bias[f];
            #pragma unroll
            for (int reg = 0; reg < 4; reg++) {
                int pp = p0 + mt * 16 + quad * 4 + reg;
                float fcv = b2f(fcu[(size_t)pp * 512 + f]);
                out[(size_t)pp * 256 + f] = fmaxf(acc[mt][nt][reg] + bv, 0.f) + fcv;
            }
        }
    }
}

// ---------------- launch ----------------
extern "C" void kernel_launch(void* const* d_in, const int* in_sizes, int n_in,
                              void* d_out, int out_size, void* d_ws, size_t ws_size,
                              hipStream_t stream) {
    const float* fine       = (const float*)d_in[0];
    const float* coarse     = (const float*)d_in[1];
    const float* fs_attn_w  = (const float*)d_in[2];
    const float* fs_conv_w  = (const float*)d_in[3];
    const float* offset_w   = (const float*)d_in[4];
    const float* om_w       = (const float*)d_in[5];
    const float* om_b       = (const float*)d_in[6];
    const float* dcn_kernel = (const float*)d_in[7];
    const float* dcn_bias   = (const float*)d_in[8];
    float* out = (float*)d_out;

    // workspace layout (~35.4 MB)
    char* ws = (char*)d_ws;
    size_t off = 0;
    float* gap_part = (float*)(ws + off); off += 131072;      // 128x256 f32 partials
    u16*   fcu = (u16*)(ws + off);   off += 16777216ull;
    float* om  = (float*)(ws + off); off += 14155776ull;
    u16*   wtf = (u16*)(ws + off);   off += 2359296ull;
    u16*   wkt = (u16*)(ws + off);   off += 1179648ull;
    u16*   wb0 = (u16*)(ws + off);   off += 131072ull;
    u16*   bomw = (u16*)(ws + off);  off += 2359296ull;

    k_pre<<<1536, 256, 0, stream>>>(fine, coarse, fs_conv_w, dcn_kernel, om_w,
                                    gap_part, fcu, wb0, wkt, bomw);
    k_mid<<<656, 256, 0, stream>>>(fine, gap_part, fs_attn_w, wb0, fcu,
                                   offset_w, bomw, wtf);
    k_conv<<<1024, 256, 0, stream>>>(fcu, wtf, om_b, om);
    k_dcn<<<512, 512, 0, stream>>>(fcu, om, wkt, dcn_bias, out);
}

// Round 15
// 205.282 us; speedup vs baseline: 1.2973x; 1.2973x over previous
//
#include <hip/hip_runtime.h>
#include <hip/hip_bf16.h>

using u16 = unsigned short;
typedef __attribute__((ext_vector_type(8))) short short8;
typedef __attribute__((ext_vector_type(4))) float floatx4;
typedef __attribute__((ext_vector_type(4))) unsigned int uintx4;

__device__ __forceinline__ float b2f(u16 u) {
    union { unsigned int i; float f; } v; v.i = ((unsigned int)u) << 16; return v.f;
}
__device__ __forceinline__ u16 f2b(float f) {
    __hip_bfloat16 h = __float2bfloat16(f);
    u16 u; __builtin_memcpy(&u, &h, sizeof(u)); return u;
}

// B=4, fine 64x64x256, coarse 32x32x256, F=256, DG=8, KK=9, om ch=216
// Inputs fp32; OUTPUT fp32. fcu = concat(fine_cal, coarse_up) bf16 interleaved.
// wtf/wkt/wb0/bomw: weights in MFMA fragment order [ksg][ntile][lane][8].
// XCD-slab swizzle: XCD (bx&7) owns global rows [xcd*32, xcd*32+32).
// Round-15: REVERT k_conv to round-13 form. Round-14's dual-K-stream broke L2
// locality (FETCH 17.7->183 MB, WRITE 13.8->62 MB, dur 57->111us). k_conv is
// declared at its structural floor (~55us) after 5 failed schedule/ILP attacks.

// ---------------- k_pre: gap partials (128) | upsample (512) | wswz (896) -------
__global__ __launch_bounds__(256) void k_pre(const float* __restrict__ fine,
                                             const float* __restrict__ coarse,
                                             const float* __restrict__ fsw,
                                             const float* __restrict__ Wk,
                                             const float* __restrict__ omw,
                                             float* __restrict__ gap_part,
                                             u16* __restrict__ fcu,
                                             u16* __restrict__ wb0,
                                             u16* __restrict__ wkt,
                                             u16* __restrict__ bomw) {
    int bxg = blockIdx.x;
    int tid = threadIdx.x;
    if (bxg < 128) {
        int b = bxg >> 5, chunk = bxg & 31, c = tid;
        const float* p = fine + ((size_t)b * 4096 + (size_t)chunk * 128) * 256 + c;
        float s = 0.f;
        for (int i = 0; i < 128; i++) s += p[(size_t)i * 256];
        gap_part[(size_t)bxg * 256 + c] = s;
        return;
    }
    if (bxg < 640) {
        int p = (bxg - 128) * 32 + (tid >> 3);
        int ch = (tid & 7) * 32;
        int b = p >> 12, y = (p & 4095) >> 6, x = p & 63;
        float sy = fminf(fmaxf(0.5f * y - 0.25f, 0.0f), 31.0f);
        float sx = fminf(fmaxf(0.5f * x - 0.25f, 0.0f), 31.0f);
        int y0 = (int)floorf(sy); float wy = sy - (float)y0; int y1 = min(y0 + 1, 31);
        int x0 = (int)floorf(sx); float wx = sx - (float)x0; int x1 = min(x0 + 1, 31);
        float w00 = (1.f - wy) * (1.f - wx), w01 = (1.f - wy) * wx;
        float w10 = wy * (1.f - wx), w11 = wy * wx;
        const float* c00 = coarse + ((size_t)((b * 32 + y0) * 32 + x0)) * 256 + ch;
        const float* c01 = coarse + ((size_t)((b * 32 + y0) * 32 + x1)) * 256 + ch;
        const float* c10 = coarse + ((size_t)((b * 32 + y1) * 32 + x0)) * 256 + ch;
        const float* c11 = coarse + ((size_t)((b * 32 + y1) * 32 + x1)) * 256 + ch;
        u16* dst = fcu + (size_t)p * 512 + 256 + ch;
        #pragma unroll
        for (int k = 0; k < 4; k++) {
            float4 a0 = *(const float4*)(c00 + k * 8), a1v = *(const float4*)(c00 + k * 8 + 4);
            float4 b0 = *(const float4*)(c01 + k * 8), b1v = *(const float4*)(c01 + k * 8 + 4);
            float4 g0 = *(const float4*)(c10 + k * 8), g1 = *(const float4*)(c10 + k * 8 + 4);
            float4 d0 = *(const float4*)(c11 + k * 8), d1 = *(const float4*)(c11 + k * 8 + 4);
            u16 o[8] = {
                f2b(w00 * a0.x + w01 * b0.x + w10 * g0.x + w11 * d0.x),
                f2b(w00 * a0.y + w01 * b0.y + w10 * g0.y + w11 * d0.y),
                f2b(w00 * a0.z + w01 * b0.z + w10 * g0.z + w11 * d0.z),
                f2b(w00 * a0.w + w01 * b0.w + w10 * g0.w + w11 * d0.w),
                f2b(w00 * a1v.x + w01 * b1v.x + w10 * g1.x + w11 * d1.x),
                f2b(w00 * a1v.y + w01 * b1v.y + w10 * g1.y + w11 * d1.y),
                f2b(w00 * a1v.z + w01 * b1v.z + w10 * g1.z + w11 * d1.z),
                f2b(w00 * a1v.w + w01 * b1v.w + w10 * g1.w + w11 * d1.w)};
            uint4 ov; __builtin_memcpy(&ov, o, 16);
            *(uint4*)(dst + k * 8) = ov;
        }
        return;
    }
    int bx = bxg - 640;
    if (bx < 32) {
        int idx = bx * 256 + tid;
        int lane = idx & 63, nt = (idx >> 6) & 15, ks = idx >> 10;
        int n = nt * 16 + (lane & 15);
        int k0 = ks * 32 + (lane >> 4) * 8;
        u16 tmp[8];
        #pragma unroll
        for (int j = 0; j < 8; j++) tmp[j] = f2b(fsw[(size_t)(k0 + j) * 256 + n]);
        uint4 v; __builtin_memcpy(&v, tmp, 16);
        *(uint4*)(wb0 + (size_t)idx * 8) = v;
    } else if (bx < 320) {
        int idx = (bx - 32) * 256 + tid;
        int lane = idx & 63, nt = (idx >> 6) & 15, ks = idx >> 10;
        int n = nt * 16 + (lane & 15);
        int k0 = ks * 32 + (lane >> 4) * 8;
        u16 tmp[8];
        #pragma unroll
        for (int j = 0; j < 8; j++) tmp[j] = f2b(Wk[(size_t)(k0 + j) * 256 + n]);
        uint4 v; __builtin_memcpy(&v, tmp, 16);
        *(uint4*)(wkt + (size_t)idx * 8) = v;
    } else {
        int idx = (bx - 320) * 256 + tid;
        int lane = idx & 63, nt = (idx >> 6) & 15, ks = (idx >> 10) & 15, t = idx >> 14;
        int n = nt * 16 + (lane & 15);
        int f0 = ks * 32 + (lane >> 4) * 8;
        u16 tmp[8];
        #pragma unroll
        for (int j = 0; j < 8; j++)
            tmp[j] = (n < 216) ? f2b(omw[((size_t)t * 512 + f0 + j) * 216 + n]) : (u16)0;
        uint4 v; __builtin_memcpy(&v, tmp, 16);
        *(uint4*)(bomw + (size_t)idx * 8) = v;
    }
}

// ---------------- k_mid: g0 (512, with inline attn GEMV) | weff (144) -----------
__global__ __launch_bounds__(256) void k_mid(const float* __restrict__ fine,
                                             const float* __restrict__ gap_part,
                                             const float* __restrict__ attw,
                                             const u16* __restrict__ wb,
                                             u16* __restrict__ fcu,
                                             const float* __restrict__ ow,
                                             const u16* __restrict__ bomw,
                                             u16* __restrict__ wtf) {
    __shared__ u16 smem[32 * 520];
    int bxg = blockIdx.x;
    int tid = threadIdx.x;
    int lane = tid & 63, wid = tid >> 6;
    int r = lane & 15, quad = lane >> 4;
    if (bxg < 512) {
        u16* cols = smem;
        float* gaprow = (float*)(smem + 32 * 264);
        float* a1row  = (float*)(smem + 32 * 264 + 512);
        int m0 = bxg * 32;
        int b = m0 >> 12;
        {
            const float* gp = gap_part + (size_t)b * 32 * 256 + tid;
            float gsum = 0.f;
            #pragma unroll
            for (int k = 0; k < 32; k++) gsum += gp[(size_t)k * 256];
            gaprow[tid] = gsum;
        }
        __syncthreads();
        {
            const float* wcol = attw + tid;
            float s = 0.f;
            #pragma unroll 8
            for (int c = 0; c < 256; c++) s += gaprow[c] * wcol[(size_t)c * 256];
            s *= (1.0f / 4096.0f);
            a1row[tid] = 1.0f + 1.0f / (1.0f + expf(-s));
        }
        __syncthreads();
        int sp = tid >> 3, coff = (tid & 7) * 32;
        int row = m0 + sp;
        {
            const float* src = fine + (size_t)row * 256 + coff;
            u16* dst = &cols[sp * 264 + coff];
            #pragma unroll
            for (int ch = 0; ch < 4; ch++) {
                float4 v0 = *(const float4*)(src + ch * 8);
                float4 v1 = *(const float4*)(src + ch * 8 + 4);
                float4 s0 = *(const float4*)(&a1row[coff + ch * 8]);
                float4 s1 = *(const float4*)(&a1row[coff + ch * 8 + 4]);
                u16 o[8] = {f2b(v0.x * s0.x), f2b(v0.y * s0.y), f2b(v0.z * s0.z), f2b(v0.w * s0.w),
                            f2b(v1.x * s1.x), f2b(v1.y * s1.y), f2b(v1.z * s1.z), f2b(v1.w * s1.w)};
                uint4 ov; __builtin_memcpy(&ov, o, 16);
                *(uint4*)(dst + ch * 8) = ov;
            }
        }
        __syncthreads();
        floatx4 acc[2][4];
        #pragma unroll
        for (int i = 0; i < 2; i++)
            #pragma unroll
            for (int j = 0; j < 4; j++) acc[i][j] = (floatx4){0.f, 0.f, 0.f, 0.f};
        #pragma unroll
        for (int ks = 0; ks < 8; ks++) {
            short8 a0 = *(const short8*)&cols[r * 264 + ks * 32 + quad * 8];
            short8 a1v = *(const short8*)&cols[(16 + r) * 264 + ks * 32 + quad * 8];
            const u16* bp = wb + (((size_t)ks * 16 + wid * 4) * 64 + lane) * 8;
            short8 b0 = *(const short8*)(bp);
            short8 b1 = *(const short8*)(bp + 512);
            short8 b2 = *(const short8*)(bp + 1024);
            short8 b3 = *(const short8*)(bp + 1536);
            acc[0][0] = __builtin_amdgcn_mfma_f32_16x16x32_bf16(a0, b0, acc[0][0], 0, 0, 0);
            acc[0][1] = __builtin_amdgcn_mfma_f32_16x16x32_bf16(a0, b1, acc[0][1], 0, 0, 0);
            acc[0][2] = __builtin_amdgcn_mfma_f32_16x16x32_bf16(a0, b2, acc[0][2], 0, 0, 0);
            acc[0][3] = __builtin_amdgcn_mfma_f32_16x16x32_bf16(a0, b3, acc[0][3], 0, 0, 0);
            acc[1][0] = __builtin_amdgcn_mfma_f32_16x16x32_bf16(a1v, b0, acc[1][0], 0, 0, 0);
            acc[1][1] = __builtin_amdgcn_mfma_f32_16x16x32_bf16(a1v, b1, acc[1][1], 0, 0, 0);
            acc[1][2] = __builtin_amdgcn_mfma_f32_16x16x32_bf16(a1v, b2, acc[1][2], 0, 0, 0);
            acc[1][3] = __builtin_amdgcn_mfma_f32_16x16x32_bf16(a1v, b3, acc[1][3], 0, 0, 0);
        }
        #pragma unroll
        for (int mt = 0; mt < 2; mt++)
            #pragma unroll
            for (int nt = 0; nt < 4; nt++) {
                int f = wid * 64 + nt * 16 + r;
                #pragma unroll
                for (int reg = 0; reg < 4; reg++) {
                    int pp = m0 + mt * 16 + quad * 4 + reg;
                    fcu[(size_t)pp * 512 + f] = f2b(acc[mt][nt][reg]);
                }
            }
        return;
    }
    int i = bxg - 512;
    int c0 = (i & 15) * 32, t = i >> 4;
    u16* cols = smem;
    int sp = tid >> 3, f0 = (tid & 7) * 64;
    {
        const float* src = ow + (size_t)(c0 + sp) * 512 + f0;
        u16* dst = &cols[sp * 520 + f0];
        #pragma unroll
        for (int k = 0; k < 8; k++) {
            float4 v0 = *(const float4*)(src + k * 8);
            float4 v1 = *(const float4*)(src + k * 8 + 4);
            u16 o[8] = {f2b(v0.x), f2b(v0.y), f2b(v0.z), f2b(v0.w),
                        f2b(v1.x), f2b(v1.y), f2b(v1.z), f2b(v1.w)};
            uint4 ov; __builtin_memcpy(&ov, o, 16);
            *(uint4*)(dst + k * 8) = ov;
        }
    }
    __syncthreads();
    floatx4 acc[2][4];
    #pragma unroll
    for (int ii = 0; ii < 2; ii++)
        #pragma unroll
        for (int j = 0; j < 4; j++) acc[ii][j] = (floatx4){0.f, 0.f, 0.f, 0.f};
    #pragma unroll
    for (int ks = 0; ks < 16; ks++) {
        short8 a0 = *(const short8*)&cols[r * 520 + ks * 32 + quad * 8];
        short8 a1v = *(const short8*)&cols[(16 + r) * 520 + ks * 32 + quad * 8];
        const u16* bp = bomw + (((size_t)(t * 16 + ks) * 16 + wid * 4) * 64 + lane) * 8;
        short8 b0 = *(const short8*)(bp);
        short8 b1 = *(const short8*)(bp + 512);
        short8 b2 = *(const short8*)(bp + 1024);
        short8 b3 = *(const short8*)(bp + 1536);
        acc[0][0] = __builtin_amdgcn_mfma_f32_16x16x32_bf16(a0, b0, acc[0][0], 0, 0, 0);
        acc[0][1] = __builtin_amdgcn_mfma_f32_16x16x32_bf16(a0, b1, acc[0][1], 0, 0, 0);
        acc[0][2] = __builtin_amdgcn_mfma_f32_16x16x32_bf16(a0, b2, acc[0][2], 0, 0, 0);
        acc[0][3] = __builtin_amdgcn_mfma_f32_16x16x32_bf16(a0, b3, acc[0][3], 0, 0, 0);
        acc[1][0] = __builtin_amdgcn_mfma_f32_16x16x32_bf16(a1v, b0, acc[1][0], 0, 0, 0);
        acc[1][1] = __builtin_amdgcn_mfma_f32_16x16x32_bf16(a1v, b1, acc[1][1], 0, 0, 0);
        acc[1][2] = __builtin_amdgcn_mfma_f32_16x16x32_bf16(a1v, b2, acc[1][2], 0, 0, 0);
        acc[1][3] = __builtin_amdgcn_mfma_f32_16x16x32_bf16(a1v, b3, acc[1][3], 0, 0, 0);
    }
    #pragma unroll
    for (int mt = 0; mt < 2; mt++) {
        #pragma unroll
        for (int nt = 0; nt < 4; nt++) {
            int n = wid * 64 + nt * 16 + r;
            #pragma unroll
            for (int reg = 0; reg < 4; reg++) {
                int c = c0 + mt * 16 + quad * 4 + reg;
                float sc = (c >= 256) ? 2.0f : 1.0f;
                size_t addr = (((size_t)(t * 16 + (c >> 5)) * 16 + (n >> 4)) * 64
                               + ((c >> 3) & 3) * 16 + (n & 15)) * 8 + (c & 7);
                wtf[addr] = f2b(acc[mt][nt][reg] * sc);
            }
        }
    }
}

// ---------------- stage 5: halo conv, M=32 (4x8), N=128, grid 1024 (round-13) ---
__global__ __launch_bounds__(256, 4) void k_conv(const u16* __restrict__ fcu,
                                                 const u16* __restrict__ wtf,
                                                 const float* __restrict__ bias,
                                                 float* __restrict__ om) {
    __shared__ u16 halo[2][60 * 40];
    int tid = threadIdx.x;
    int bx = blockIdx.x;
    int xcd = bx & 7, i = bx >> 3;            // i in 0..127
    int prow4 = xcd * 8 + (i >> 4);           // 4-row group 0..63
    int pcol = (i >> 1) & 7;
    int ns = i & 1;
    int b = prow4 >> 4;
    int py0 = (prow4 & 15) * 4, px0 = pcol * 8;
    int n0 = ns * 128;
    int lane = tid & 63, wid = tid >> 6;
    int r = lane & 15, quad = lane >> 4;

    int pix0 = tid >> 2, q80 = tid & 3;
    int hy0 = pix0 / 10, hx0 = pix0 - hy0 * 10;
    int gy0 = py0 - 1 + hy0, gx0 = px0 - 1 + hx0;
    bool act0 = pix0 < 60;
    bool in0 = act0 && gy0 >= 0 && gy0 < 64 && gx0 >= 0 && gx0 < 64;
    const u16* gs0 = fcu + ((size_t)((b * 64 + min(max(gy0, 0), 63)) * 64 + min(max(gx0, 0), 63))) * 512 + q80 * 8;
    int ld0 = pix0 * 40 + q80 * 8;

    floatx4 acc[2][2];
    #pragma unroll
    for (int a = 0; a < 2; a++)
        #pragma unroll
        for (int c = 0; c < 2; c++) acc[a][c] = (floatx4){0.f, 0.f, 0.f, 0.f};

    {
        uint4 v0 = make_uint4(0, 0, 0, 0);
        if (in0) v0 = *(const uint4*)(gs0);
        if (act0) *(uint4*)&halo[0][ld0] = v0;
    }
    __syncthreads();

    for (int cq = 0; cq < 16; cq++) {
        int cur = cq & 1;
        const u16* hb = &halo[cur][0];
        // B-prefetch pipeline, depth 2 taps
        short8 Bp[2][2];
        #pragma unroll
        for (int d = 0; d < 2; d++) {
            const u16* bp = wtf + (((size_t)(d * 16 + cq) * 16 + ns * 8 + wid * 2) * 64 + lane) * 8;
            Bp[d][0] = *(const short8*)(bp);
            Bp[d][1] = *(const short8*)(bp + 512);
        }
        uint4 v0 = make_uint4(0, 0, 0, 0);
        #pragma unroll
        for (int t = 0; t < 7; t++) {
            int d = t & 1;
            short8 b0 = Bp[d][0], b1 = Bp[d][1];
            const u16* bp = wtf + (((size_t)((t + 2) * 16 + cq) * 16 + ns * 8 + wid * 2) * 64 + lane) * 8;
            Bp[d][0] = *(const short8*)(bp);
            Bp[d][1] = *(const short8*)(bp + 512);
            int dy = t / 3 - 1, dx = t - (t / 3) * 3 - 1;
            short8 a[2];
            #pragma unroll
            for (int mt = 0; mt < 2; mt++) {
                int m = mt * 16 + r;
                int hy = (m >> 3) + 1 + dy, hx = (m & 7) + 1 + dx;
                a[mt] = *(const short8*)&hb[(hy * 10 + hx) * 40 + quad * 8];
            }
            #pragma unroll
            for (int mt = 0; mt < 2; mt++) {
                acc[mt][0] = __builtin_amdgcn_mfma_f32_16x16x32_bf16(a[mt], b0, acc[mt][0], 0, 0, 0);
                acc[mt][1] = __builtin_amdgcn_mfma_f32_16x16x32_bf16(a[mt], b1, acc[mt][1], 0, 0, 0);
            }
        }
        // staging load issued AFTER all B loads (no vmcnt inversion)
        if (cq < 15) {
            if (in0) v0 = *(const uint4*)(gs0 + (cq + 1) * 32);
        }
        #pragma unroll
        for (int t = 7; t < 9; t++) {
            int d = t & 1;
            short8 b0 = Bp[d][0], b1 = Bp[d][1];
            int dy = t / 3 - 1, dx = t - (t / 3) * 3 - 1;
            short8 a[2];
            #pragma unroll
            for (int mt = 0; mt < 2; mt++) {
                int m = mt * 16 + r;
                int hy = (m >> 3) + 1 + dy, hx = (m & 7) + 1 + dx;
                a[mt] = *(const short8*)&hb[(hy * 10 + hx) * 40 + quad * 8];
            }
            #pragma unroll
            for (int mt = 0; mt < 2; mt++) {
                acc[mt][0] = __builtin_amdgcn_mfma_f32_16x16x32_bf16(a[mt], b0, acc[mt][0], 0, 0, 0);
                acc[mt][1] = __builtin_amdgcn_mfma_f32_16x16x32_bf16(a[mt], b1, acc[mt][1], 0, 0, 0);
            }
        }
        if (cq < 15) {
            if (act0) *(uint4*)&halo[cur ^ 1][ld0] = v0;
        }
        __syncthreads();
    }
    #pragma unroll
    for (int nt = 0; nt < 2; nt++) {
        int n = n0 + wid * 32 + nt * 16 + r;
        if (n < 216) {
            float bv = bias[n];
            #pragma unroll
            for (int mt = 0; mt < 2; mt++) {
                #pragma unroll
                for (int reg = 0; reg < 4; reg++) {
                    int m = mt * 16 + quad * 4 + reg;
                    int gyy = py0 + (m >> 3), gxx = px0 + (m & 7);
                    size_t pix = (size_t)((b * 64 + gyy) * 64 + gxx);
                    om[pix * 216 + n] = acc[mt][nt][reg] + bv;
                }
            }
        }
    }
}

// ---------------- stage 6 helpers -----------------------------------------------
#define KEEP8(G) asm volatile("" :: "v"((G)[0][0]), "v"((G)[0][1]), \
                                    "v"((G)[1][0]), "v"((G)[1][1]), \
                                    "v"((G)[2][0]), "v"((G)[2][1]), \
                                    "v"((G)[3][0]), "v"((G)[3][1]))

__device__ __forceinline__ void dcn_addr1(int g3, int tl, int y, int xs, int ch0,
                                          float oy, float ox, float mlog,
                                          float w[4], int ofs[4]) {
    int dy = g3 - 1, dx = tl - 1;
    float mk = 2.0f / (1.0f + expf(-mlog));
    float py = (float)(y + dy) + oy;
    float px = (float)(xs + dx) + ox;
    float fy = floorf(py), fx = floorf(px);
    int iy = (int)fy, ix = (int)fx;
    float wy1 = py - fy, wx1 = px - fx;
    float wy0 = 1.f - wy1, wx0 = 1.f - wx1;
    bool y0in = iy >= 0 && iy < 64, y1in = iy >= -1 && iy < 63;
    bool x0in = ix >= 0 && ix < 64, x1in = ix >= -1 && ix < 63;
    w[0] = (y0in && x0in) ? wy0 * wx0 * mk : 0.f;
    w[1] = (y0in && x1in) ? wy0 * wx1 * mk : 0.f;
    w[2] = (y1in && x0in) ? wy1 * wx0 * mk : 0.f;
    w[3] = (y1in && x1in) ? wy1 * wx1 * mk : 0.f;
    int iy0 = min(max(iy, 0), 63), iy1 = min(max(iy + 1, 0), 63);
    int ix0 = min(max(ix, 0), 63), ix1 = min(max(ix + 1, 0), 63);
    ofs[0] = (iy0 * 64 + ix0) * 512 + ch0;
    ofs[1] = (iy0 * 64 + ix1) * 512 + ch0;
    ofs[2] = (iy1 * 64 + ix0) * 512 + ch0;
    ofs[3] = (iy1 * 64 + ix1) * 512 + ch0;
}

__device__ __forceinline__ void dcn_issue(uintx4 G[4][2], const u16* __restrict__ cub,
                                          const int ofs[4]) {
    #pragma unroll
    for (int c = 0; c < 4; c++) {
        const u16* p = cub + ofs[c];
        G[c][0] = *(const uintx4*)(p);
        G[c][1] = *(const uintx4*)(p + 8);
    }
}

__device__ __forceinline__ void dcn_blend(const uintx4 G[4][2], const float w[4],
                                          u16* __restrict__ dst) {
    #pragma unroll
    for (int k = 0; k < 2; k++) {
        const u16* q0 = (const u16*)&G[0][k];
        const u16* q1 = (const u16*)&G[1][k];
        const u16* q2 = (const u16*)&G[2][k];
        const u16* q3 = (const u16*)&G[3][k];
        u16 o[8];
        #pragma unroll
        for (int j = 0; j < 8; j++) {
            float v = w[0] * b2f(q0[j]) + w[1] * b2f(q1[j])
                    + w[2] * b2f(q2[j]) + w[3] * b2f(q3[j]);
            o[j] = f2b(v);
        }
        uint4 ov; __builtin_memcpy(&ov, o, 16);
        *(uint4*)(dst + k * 8) = ov;
    }
}

// ---------------- stage 6: fused DCN, keepalive-forced depth-2 gather pipeline --
__global__ __launch_bounds__(512, 2) void k_dcn(const u16* __restrict__ fcu,
                                                const float* __restrict__ om,
                                                const u16* __restrict__ bfr,
                                                const float* __restrict__ bias,
                                                float* __restrict__ out) {
    __shared__ u16 cols[32 * 776];
    int tid = threadIdx.x;
    int bx = blockIdx.x;
    int xcd = bx & 7, i = bx >> 3;             // i in 0..63
    int grow = xcd * 32 + (i >> 1);            // global row 0..255
    int p0 = grow * 64 + (i & 1) * 32;         // 32-pixel strip
    int b = p0 >> 12;
    int y = (p0 & 4095) >> 6;
    int x0 = p0 & 63;
    int lane = tid & 63, wid = tid >> 6;       // wid 0..7
    int r = lane & 15, quad = lane >> 4;
    int sp = tid >> 4;                          // pixel in strip 0..31
    int sgh = tid & 15;                         // group-half
    int g = sgh >> 1, h = sgh & 1;
    int ch0 = g * 32 + h * 16;
    int pix = p0 + sp;
    int xs = x0 + sp;
    const u16* cub = fcu + ((size_t)b * 4096) * 512 + 256;
    const float* omp = om + (size_t)pix * 216;
    u16* mydst = &cols[0] + sp * 776 + ch0;

    floatx4 acc[2][2];
    #pragma unroll
    for (int a = 0; a < 2; a++)
        #pragma unroll
        for (int c = 0; c < 2; c++) acc[a][c] = (floatx4){0.f, 0.f, 0.f, 0.f};

    #pragma unroll
    for (int g3 = 0; g3 < 3; g3++) {
        float oy[3], ox[3], mm[3];
        #pragma unroll
        for (int tl = 0; tl < 3; tl++) {
            int t = g3 * 3 + tl;
            oy[tl] = omp[g * 18 + 2 * t];
            ox[tl] = omp[g * 18 + 2 * t + 1];
            mm[tl] = omp[144 + g * 9 + t];
        }
        float w0[4], w1[4], w2[4];
        int o0[4], o1[4], o2[4];
        uintx4 G0[4][2], G1[4][2], G2[4][2];
        dcn_addr1(g3, 0, y, xs, ch0, oy[0], ox[0], mm[0], w0, o0);
        dcn_issue(G0, cub, o0);
        dcn_addr1(g3, 1, y, xs, ch0, oy[1], ox[1], mm[1], w1, o1);
        dcn_issue(G1, cub, o1);
        __builtin_amdgcn_sched_barrier(0);
        KEEP8(G0);
        __builtin_amdgcn_sched_barrier(0);
        dcn_blend(G0, w0, mydst + 0 * 256);
        dcn_addr1(g3, 2, y, xs, ch0, oy[2], ox[2], mm[2], w2, o2);
        dcn_issue(G2, cub, o2);
        __builtin_amdgcn_sched_barrier(0);
        KEEP8(G1);
        __builtin_amdgcn_sched_barrier(0);
        dcn_blend(G1, w1, mydst + 1 * 256);
        KEEP8(G2);
        __builtin_amdgcn_sched_barrier(0);
        dcn_blend(G2, w2, mydst + 2 * 256);
        __syncthreads();
        short8 Bb[4][2];
        #pragma unroll
        for (int d = 0; d < 4; d++) {
            const u16* bp = bfr + (((size_t)(g3 * 24 + d) * 16 + wid * 2) * 64 + lane) * 8;
            Bb[d][0] = *(const short8*)(bp);
            Bb[d][1] = *(const short8*)(bp + 512);
        }
        #pragma unroll
        for (int ksl = 0; ksl < 24; ksl++) {
            int d = ksl & 3;
            short8 b0 = Bb[d][0], b1 = Bb[d][1];
            if (ksl + 4 < 24) {
                const u16* bp = bfr + (((size_t)(g3 * 24 + ksl + 4) * 16 + wid * 2) * 64 + lane) * 8;
                Bb[d][0] = *(const short8*)(bp);
                Bb[d][1] = *(const short8*)(bp + 512);
            }
            short8 a0 = *(const short8*)&cols[r * 776 + ksl * 32 + quad * 8];
            short8 a1 = *(const short8*)&cols[(16 + r) * 776 + ksl * 32 + quad * 8];
            acc[0][0] = __builtin_amdgcn_mfma_f32_16x16x32_bf16(a0, b0, acc[0][0], 0, 0, 0);
            acc[0][1] = __builtin_amdgcn_mfma_f32_16x16x32_bf16(a0, b1, acc[0][1], 0, 0, 0);
            acc[1][0] = __builtin_amdgcn_mfma_f32_16x16x32_bf16(a1, b0, acc[1][0], 0, 0, 0);
            acc[1][1] = __builtin_amdgcn_mfma_f32_16x16x32_bf16(a1, b1, acc[1][1], 0, 0, 0);
        }
        __syncthreads();
    }
    #pragma unroll
    for (int mt = 0; mt < 2; mt++) {
        #pragma unroll
        for (int nt = 0; nt < 2; nt++) {
            int f = wid * 32 + nt * 16 + r;
            float bv = bias[f];
            #pragma unroll
            for (int reg = 0; reg < 4; reg++) {
                int pp = p0 + mt * 16 + quad * 4 + reg;
                float fcv = b2f(fcu[(size_t)pp * 512 + f]);
                out[(size_t)pp * 256 + f] = fmaxf(acc[mt][nt][reg] + bv, 0.f) + fcv;
            }
        }
    }
}

// ---------------- launch ----------------
extern "C" void kernel_launch(void* const* d_in, const int* in_sizes, int n_in,
                              void* d_out, int out_size, void* d_ws, size_t ws_size,
                              hipStream_t stream) {
    const float* fine       = (const float*)d_in[0];
    const float* coarse     = (const float*)d_in[1];
    const float* fs_attn_w  = (const float*)d_in[2];
    const float* fs_conv_w  = (const float*)d_in[3];
    const float* offset_w   = (const float*)d_in[4];
    const float* om_w       = (const float*)d_in[5];
    const float* om_b       = (const float*)d_in[6];
    const float* dcn_kernel = (const float*)d_in[7];
    const float* dcn_bias   = (const float*)d_in[8];
    float* out = (float*)d_out;

    // workspace layout (~35.4 MB)
    char* ws = (char*)d_ws;
    size_t off = 0;
    float* gap_part = (float*)(ws + off); off += 131072;      // 128x256 f32 partials
    u16*   fcu = (u16*)(ws + off);   off += 16777216ull;
    float* om  = (float*)(ws + off); off += 14155776ull;
    u16*   wtf = (u16*)(ws + off);   off += 2359296ull;
    u16*   wkt = (u16*)(ws + off);   off += 1179648ull;
    u16*   wb0 = (u16*)(ws + off);   off += 131072ull;
    u16*   bomw = (u16*)(ws + off);  off += 2359296ull;

    k_pre<<<1536, 256, 0, stream>>>(fine, coarse, fs_conv_w, dcn_kernel, om_w,
                                    gap_part, fcu, wb0, wkt, bomw);
    k_mid<<<656, 256, 0, stream>>>(fine, gap_part, fs_attn_w, wb0, fcu,
                                   offset_w, bomw, wtf);
    k_conv<<<1024, 256, 0, stream>>>(fcu, wtf, om_b, om);
    k_dcn<<<512, 512, 0, stream>>>(fcu, om, wkt, dcn_bias, out);
}